// Round 1
// baseline (3435.462 us; speedup 1.0000x reference)
//
#include <hip/hip_runtime.h>
#include <cfloat>
#include <cmath>

// Problem constants
#define SN 8
#define DN 64
#define KN 512
#define NN 16384            // B*T
#define CK 128              // K-chunk staged in LDS
#define REPAIR_THR 1e-2f    // fp32 d2 noise ~1e-5; 1000x margin
#define MAXFLAG 65536

// workspace layout (float indices)
#define WS_CNT 0
#define WS_SCL 16
#define WS_OFF (16 + SN*DN)           // 528
#define WS_E2  (WS_OFF + SN*DN)       // 1040
#define WS_ENT (WS_E2 + SN*KN)        // 5136

// ---------------------------------------------------------------- prep ------
__global__ void prep_kernel(const float* __restrict__ b, const float* __restrict__ gamma,
                            const float* __restrict__ beta, const float* __restrict__ bmean,
                            const float* __restrict__ bvar, const float* __restrict__ E,
                            float* __restrict__ ws) {
    int tid = blockIdx.x * 256 + threadIdx.x;
    if (tid < SN * KN) {                       // ||E_k||^2 in fp64, stored fp32
        const float* er = E + (size_t)tid * DN;
        double a = 0.0;
        for (int d = 0; d < DN; ++d) { double v = (double)er[d]; a = fma(v, v, a); }
        ws[WS_E2 + tid] = (float)a;
    }
    int u = tid - SN * KN;
    if (u >= 0 && u < SN * DN) {               // fold BN+bias: bn = proj*scl + off
        double inv = 1.0 / sqrt((double)bvar[u] + 0.001);
        double sc  = (double)gamma[u] * inv;
        ws[WS_SCL + u] = (float)sc;
        ws[WS_OFF + u] = (float)(((double)b[u] - (double)bmean[u]) * sc + (double)beta[u]);
    }
}

// ---------------------------------------------------------------- main ------
// block: 256 threads = 16 tg (4 t each) x 16 lg. 64 positions/block, 256 blocks.
__launch_bounds__(256, 1)
__global__ void main_kernel(const float* __restrict__ x, const float* __restrict__ W,
                            const float* __restrict__ E, float* __restrict__ ws,
                            float* __restrict__ out, int entcap) {
    extern __shared__ float4 sm4[];
    float4* xs4 = sm4;                 // 64 rows x 17 f4 (pad)  = 1088
    float4* ws4 = sm4 + 64 * 17;       // 64 rows x 16 f4        = 1024
    float4* zs4 = ws4 + 64 * 16;       // 64 rows x 17 f4 (pad)  = 1088
    float4* es4 = zs4 + 64 * 17;       // 128 rows x 17 f4 (pad) = 2176
    float*  tail = (float*)(es4 + 128 * 17);
    float* e2s = tail;                 // 128
    float* scl = tail + 128;           // 64
    float* ofl = tail + 192;           // 64
    float* zzs = tail + 256;           // 64
    // total = 5376*16 + 320*4 = 87296 B -> 1 block/CU

    const int tid = threadIdx.x;
    const int tg = tid >> 4;           // 0..15 : owns t = tg*4 + ti
    const int lg = tid & 15;           // 0..15 : e-cols (phase C) / k-lanes (phase D)
    const int n0 = blockIdx.x * 64;

    const float4* xg4 = (const float4*)x;
    const float4* Wg4 = (const float4*)W;
    const float4* Eg4 = (const float4*)E;

    // stage x tile (64x64) once
    #pragma unroll
    for (int r = 0; r < 4; ++r) {
        int i = r * 256 + tid;
        xs4[(i >> 4) * 17 + (i & 15)] = xg4[n0 * 16 + i];
    }

    float zq[4][4], ze[4][4];
    #pragma unroll
    for (int ti = 0; ti < 4; ++ti)
        #pragma unroll
        for (int j = 0; j < 4; ++j) { zq[ti][j] = 0.f; ze[ti][j] = 0.f; }

    for (int s = 0; s < SN; ++s) {
        __syncthreads();
        #pragma unroll
        for (int r = 0; r < 4; ++r) {          // stage W[s] (64x64, [d][e])
            int i = r * 256 + tid;
            ws4[i] = Wg4[s * 1024 + i];
        }
        if (tid < 64) { scl[tid] = ws[WS_SCL + s * 64 + tid]; ofl[tid] = ws[WS_OFF + s * 64 + tid]; }
        __syncthreads();

        // ---- phase C: proj = x @ W  (4t x 4e per thread) ----
        float pa[4][4];
        #pragma unroll
        for (int ti = 0; ti < 4; ++ti)
            #pragma unroll
            for (int j = 0; j < 4; ++j) pa[ti][j] = 0.f;

        #pragma unroll
        for (int c = 0; c < 16; ++c) {
            float4 xv[4], wv[4];
            #pragma unroll
            for (int ti = 0; ti < 4; ++ti) xv[ti] = xs4[(tg * 4 + ti) * 17 + c];
            #pragma unroll
            for (int dd = 0; dd < 4; ++dd) wv[dd] = ws4[(c * 4 + dd) * 16 + lg];
            #pragma unroll
            for (int ti = 0; ti < 4; ++ti) {
                float a0 = pa[ti][0], a1 = pa[ti][1], a2 = pa[ti][2], a3 = pa[ti][3];
                a0 = fmaf(xv[ti].x, wv[0].x, a0); a0 = fmaf(xv[ti].y, wv[1].x, a0);
                a0 = fmaf(xv[ti].z, wv[2].x, a0); a0 = fmaf(xv[ti].w, wv[3].x, a0);
                a1 = fmaf(xv[ti].x, wv[0].y, a1); a1 = fmaf(xv[ti].y, wv[1].y, a1);
                a1 = fmaf(xv[ti].z, wv[2].y, a1); a1 = fmaf(xv[ti].w, wv[3].y, a1);
                a2 = fmaf(xv[ti].x, wv[0].z, a2); a2 = fmaf(xv[ti].y, wv[1].z, a2);
                a2 = fmaf(xv[ti].z, wv[2].z, a2); a2 = fmaf(xv[ti].w, wv[3].z, a2);
                a3 = fmaf(xv[ti].x, wv[0].w, a3); a3 = fmaf(xv[ti].y, wv[1].w, a3);
                a3 = fmaf(xv[ti].z, wv[2].w, a3); a3 = fmaf(xv[ti].w, wv[3].w, a3);
                pa[ti][0] = a0; pa[ti][1] = a1; pa[ti][2] = a2; pa[ti][3] = a3;
            }
        }

        // ---- BN + softmax(row of 64 across 16 lanes x 4) + z ----
        float s0 = scl[lg * 4 + 0], s1 = scl[lg * 4 + 1], s2 = scl[lg * 4 + 2], s3 = scl[lg * 4 + 3];
        float o0 = ofl[lg * 4 + 0], o1 = ofl[lg * 4 + 1], o2 = ofl[lg * 4 + 2], o3 = ofl[lg * 4 + 3];
        #pragma unroll
        for (int ti = 0; ti < 4; ++ti) {
            int t = tg * 4 + ti;
            float v0 = fmaf(pa[ti][0], s0, o0);
            float v1 = fmaf(pa[ti][1], s1, o1);
            float v2 = fmaf(pa[ti][2], s2, o2);
            float v3 = fmaf(pa[ti][3], s3, o3);
            float mx = fmaxf(fmaxf(v0, v1), fmaxf(v2, v3));
            mx = fmaxf(mx, __shfl_xor(mx, 1)); mx = fmaxf(mx, __shfl_xor(mx, 2));
            mx = fmaxf(mx, __shfl_xor(mx, 4)); mx = fmaxf(mx, __shfl_xor(mx, 8));
            float e0 = expf(v0 - mx), e1 = expf(v1 - mx), e2v = expf(v2 - mx), e3 = expf(v3 - mx);
            float sm = e0 + e1 + e2v + e3;
            sm += __shfl_xor(sm, 1); sm += __shfl_xor(sm, 2);
            sm += __shfl_xor(sm, 4); sm += __shfl_xor(sm, 8);
            float inv = 1.0f / sm;
            float4 xv = xs4[t * 17 + lg];
            float z0 = xv.x * (e0 * inv), z1 = xv.y * (e1 * inv);
            float z2 = xv.z * (e2v * inv), z3 = xv.w * (e3 * inv);
            zs4[t * 17 + lg] = make_float4(z0, z1, z2, z3);
            float zz = z0 * z0 + z1 * z1 + z2 * z2 + z3 * z3;
            zz += __shfl_xor(zz, 1); zz += __shfl_xor(zz, 2);
            zz += __shfl_xor(zz, 4); zz += __shfl_xor(zz, 8);
            if (lg == 0) zzs[t] = zz;
            ze[ti][0] += z0; ze[ti][1] += z1; ze[ti][2] += z2; ze[ti][3] += z3;
        }

        // ---- phase D: scores z@E^T, running (min1,min2,kmin) per t ----
        float m1[4], m2[4]; int k1[4];
        #pragma unroll
        for (int ti = 0; ti < 4; ++ti) { m1[ti] = FLT_MAX; m2[ti] = FLT_MAX; k1[ti] = 0x7fffffff; }

        for (int kk = 0; kk < KN; kk += CK) {
            __syncthreads();
            #pragma unroll
            for (int r = 0; r < 8; ++r) {      // stage E chunk (128x64)
                int i = r * 256 + tid;
                es4[(i >> 4) * 17 + (i & 15)] = Eg4[(s * KN + kk) * 16 + i];
            }
            if (tid < 128) e2s[tid] = ws[WS_E2 + s * KN + kk + tid];
            __syncthreads();

            float acc[4][8];
            #pragma unroll
            for (int ti = 0; ti < 4; ++ti)
                #pragma unroll
                for (int j = 0; j < 8; ++j) acc[ti][j] = 0.f;

            #pragma unroll
            for (int c = 0; c < 16; ++c) {
                float4 zv[4], ev[8];
                #pragma unroll
                for (int ti = 0; ti < 4; ++ti) zv[ti] = zs4[(tg * 4 + ti) * 17 + c];
                #pragma unroll
                for (int j = 0; j < 8; ++j) ev[j] = es4[(lg + 16 * j) * 17 + c];
                #pragma unroll
                for (int ti = 0; ti < 4; ++ti) {
                    #pragma unroll
                    for (int j = 0; j < 8; ++j) {
                        float a = acc[ti][j];
                        a = fmaf(zv[ti].x, ev[j].x, a);
                        a = fmaf(zv[ti].y, ev[j].y, a);
                        a = fmaf(zv[ti].z, ev[j].z, a);
                        a = fmaf(zv[ti].w, ev[j].w, a);
                        acc[ti][j] = a;
                    }
                }
            }
            #pragma unroll
            for (int ti = 0; ti < 4; ++ti) {
                float zzv = zzs[tg * 4 + ti];
                #pragma unroll
                for (int j = 0; j < 8; ++j) {
                    float d2 = fmaf(-2.0f, acc[ti][j], zzv) + e2s[lg + 16 * j];
                    int kx = kk + lg + 16 * j;
                    if (d2 < m1[ti]) { m2[ti] = m1[ti]; m1[ti] = d2; k1[ti] = kx; }
                    else if (d2 < m2[ti]) { m2[ti] = d2; }
                }
            }
        }

        // cross-lane (16 lanes) lexicographic argmin + second-best merge
        #pragma unroll
        for (int mask = 1; mask <= 8; mask <<= 1) {
            #pragma unroll
            for (int ti = 0; ti < 4; ++ti) {
                float om1 = __shfl_xor(m1[ti], mask);
                int   ok1 = __shfl_xor(k1[ti], mask);
                float om2 = __shfl_xor(m2[ti], mask);
                bool better = (om1 < m1[ti]) || (om1 == m1[ti] && ok1 < k1[ti]);
                float nm2 = better ? fminf(m1[ti], om2) : fminf(om1, m2[ti]);
                if (better) { m1[ti] = om1; k1[ti] = ok1; }
                m2[ti] = nm2;
            }
        }
        #pragma unroll
        for (int ti = 0; ti < 4; ++ti) {
            int n = n0 + tg * 4 + ti;
            if (lg == 0) {
                out[2 * NN * DN + s * NN + n] = (float)k1[ti];
                if (m2[ti] - m1[ti] < REPAIR_THR) {   // near-tie -> exact fp64 repair
                    int idx = atomicAdd((int*)ws, 1);
                    if (idx < entcap) ((int*)ws)[WS_ENT + idx] = (s << 14) | n;
                }
            }
            float4 eg = Eg4[(s * KN + k1[ti]) * 16 + lg];
            zq[ti][0] += eg.x; zq[ti][1] += eg.y; zq[ti][2] += eg.z; zq[ti][3] += eg.w;
        }
    }

    float4* out4 = (float4*)out;
    #pragma unroll
    for (int ti = 0; ti < 4; ++ti) {
        int n = n0 + tg * 4 + ti;
        out4[n * 16 + lg] = make_float4(zq[ti][0], zq[ti][1], zq[ti][2], zq[ti][3]);
        out4[NN * 16 + n * 16 + lg] = make_float4(ze[ti][0], ze[ti][1], ze[ti][2], ze[ti][3]);
    }
}

// ---------------------------------------------------------------- repair ----
// Exact fp64 recompute for flagged near-tie positions; patches z_k and z_q.
__global__ void repair_kernel(const float* __restrict__ x, const float* __restrict__ W,
                              const float* __restrict__ b, const float* __restrict__ gamma,
                              const float* __restrict__ beta, const float* __restrict__ bmean,
                              const float* __restrict__ bvar, const float* __restrict__ E,
                              float* __restrict__ ws, float* __restrict__ out, int entcap) {
    __shared__ double zd[64];
    __shared__ double red[256];
    __shared__ int redk[256];
    __shared__ double zzsh;
    __shared__ int shk[2];
    int cnt = ((int*)ws)[0]; if (cnt > entcap) cnt = entcap;
    const int tid = threadIdx.x;
    for (int idx = blockIdx.x; idx < cnt; idx += gridDim.x) {
        int code = ((int*)ws)[WS_ENT + idx];
        int s = code >> 14, n = code & (NN - 1);
        int e = tid & 63, q = tid >> 6;
        double p = 0.0;
        for (int d = q * 16; d < q * 16 + 16; ++d)
            p = fma((double)x[n * 64 + d], (double)W[((size_t)s * 64 + d) * 64 + e], p);
        red[tid] = p;
        __syncthreads();
        if (tid < 64) {
            double proj = (red[tid] + red[tid + 64]) + (red[tid + 128] + red[tid + 192]);
            double inv = 1.0 / sqrt((double)bvar[s * 64 + e] + 0.001);
            double bn = (double)gamma[s * 64 + e] * ((proj + (double)b[s * 64 + e]) - (double)bmean[s * 64 + e]) * inv
                      + (double)beta[s * 64 + e];
            zd[e] = bn;
        }
        __syncthreads();
        if (tid == 0) {
            double m = zd[0];
            for (int i = 1; i < 64; ++i) m = fmax(m, zd[i]);
            double sm = 0.0;
            for (int i = 0; i < 64; ++i) { double t = exp(zd[i] - m); zd[i] = t; sm += t; }
            double zz = 0.0;
            for (int i = 0; i < 64; ++i) { double z = (double)x[n * 64 + i] * (zd[i] / sm); zd[i] = z; zz = fma(z, z, zz); }
            zzsh = zz;
        }
        __syncthreads();
        double bv = DBL_MAX; int bk = 1 << 30;
        for (int k = tid; k < KN; k += 256) {
            const float* er = E + ((size_t)s * KN + k) * 64;
            double dot = 0.0, e2 = 0.0;
            for (int d = 0; d < 64; ++d) { double ed = (double)er[d]; dot = fma(zd[d], ed, dot); e2 = fma(ed, ed, e2); }
            double d2 = (zzsh - 2.0 * dot) + e2;
            if (d2 < bv) { bv = d2; bk = k; }
        }
        red[tid] = bv; redk[tid] = bk;
        __syncthreads();
        if (tid == 0) {
            double m = red[0]; int mk = redk[0];
            for (int i = 1; i < 256; ++i)
                if (red[i] < m || (red[i] == m && redk[i] < mk)) { m = red[i]; mk = redk[i]; }
            int kold = (int)(out[2 * NN * 64 + s * NN + n] + 0.5f);
            shk[0] = mk; shk[1] = kold;
            out[2 * NN * 64 + s * NN + n] = (float)mk;
        }
        __syncthreads();
        int mk = shk[0], kold = shk[1];
        if (mk != kold && tid < 64)
            atomicAdd(out + n * 64 + tid, E[((size_t)s * KN + mk) * 64 + tid] - E[((size_t)s * KN + kold) * 64 + tid]);
        __syncthreads();
    }
}

// ---------------------------------------------------------------- launch ----
extern "C" void kernel_launch(void* const* d_in, const int* in_sizes, int n_in,
                              void* d_out, int out_size, void* d_ws, size_t ws_size,
                              hipStream_t stream) {
    const float* x     = (const float*)d_in[0];
    const float* W     = (const float*)d_in[1];
    const float* b     = (const float*)d_in[2];
    const float* gamma = (const float*)d_in[3];
    const float* beta  = (const float*)d_in[4];
    const float* bmean = (const float*)d_in[5];
    const float* bvar  = (const float*)d_in[6];
    const float* E     = (const float*)d_in[7];
    float* out = (float*)d_out;
    float* ws  = (float*)d_ws;

    long avail = (long)(ws_size / 4) - WS_ENT - 16;
    if (avail < 0) avail = 0;
    int entcap = (int)(avail > MAXFLAG ? MAXFLAG : avail);

    hipFuncSetAttribute((const void*)main_kernel, hipFuncAttributeMaxDynamicSharedMemorySize, 87296);

    hipMemsetAsync(d_ws, 0, 64, stream);                 // zero flag counter
    prep_kernel<<<18, 256, 0, stream>>>(b, gamma, beta, bmean, bvar, E, ws);
    main_kernel<<<256, 256, 87296, stream>>>(x, W, E, ws, out, entcap);
    repair_kernel<<<256, 256, 0, stream>>>(x, W, b, gamma, beta, bmean, bvar, E, ws, out, entcap);
}